// Round 15
// baseline (219.836 us; speedup 1.0000x reference)
//
#include <hip/hip_runtime.h>
#include <hip/hip_bf16.h>

#define IN_DIM  64
#define HID     128
#define OUT_DIM 32
#define LOG2E_F 1.4426950408889634f
#define LN2_F   0.6931471805599453f

typedef short    v8s __attribute__((ext_vector_type(8)));
typedef float    v4f __attribute__((ext_vector_type(4)));
typedef unsigned v4u __attribute__((ext_vector_type(4)));

__device__ __forceinline__ unsigned pk2(float a, float b) {
    __hip_bfloat162 p = __float22bfloat162_rn(make_float2(a, b));
    return *(unsigned*)&p;
}
// single-instruction HW pack (RNE): lo->bits[15:0], hi->bits[31:16]
__device__ __forceinline__ unsigned pk2hw(float lo, float hi) {
    unsigned r;
    asm("v_cvt_pk_bf16_f32 %0, %1, %2" : "=v"(r) : "v"(lo), "v"(hi));
    return r;
}
// raw v_exp_f32 (2^x), no libm wrapper/fixup
__device__ __forceinline__ float exp2raw(float x) {
    float r;
    asm("v_exp_f32 %0, %1" : "=v"(r) : "v"(x));
    return r;
}

// Scaled-domain grouped-reciprocal swish, 8 values per v_rcp.
// Input v' = v_true*log2e; sigma = 1/(1+2^-v'); returns s = v'*sigma =
// swish(v_true)*log2e (exactly next layer's input scale; wo *ln2 at staging).
// Clamp m at 14: product (2^14+1)^8 ~ 2^112 < FLT_MAX; sigma exact AT the
// boundary, floored to 1/(1+2^14)=6.1e-5 beyond (true swish there ~1e-4) ->
// H error <= 2e-3, ~10x below current absmax.
__device__ __forceinline__ void swish8x(v4f a, v4f b, v4f& sa, v4f& sb) {
    float m0 = fminf(-a[0], 14.0f), m1 = fminf(-a[1], 14.0f);
    float m2 = fminf(-a[2], 14.0f), m3 = fminf(-a[3], 14.0f);
    float m4 = fminf(-b[0], 14.0f), m5 = fminf(-b[1], 14.0f);
    float m6 = fminf(-b[2], 14.0f), m7 = fminf(-b[3], 14.0f);
    float w0 = 1.0f + exp2raw(m0), w1 = 1.0f + exp2raw(m1);
    float w2 = 1.0f + exp2raw(m2), w3 = 1.0f + exp2raw(m3);
    float w4 = 1.0f + exp2raw(m4), w5 = 1.0f + exp2raw(m5);
    float w6 = 1.0f + exp2raw(m6), w7 = 1.0f + exp2raw(m7);
    float w01 = w0 * w1, w23 = w2 * w3, w45 = w4 * w5, w67 = w6 * w7;
    float p03 = w01 * w23, p47 = w45 * w67;
    float r   = __builtin_amdgcn_rcpf(p03 * p47);
    float r03 = r * p47, r47 = r * p03;           // 1/p03, 1/p47
    float r01 = r03 * w23, r23 = r03 * w01;       // 1/w01, 1/w23
    float r45 = r47 * w67, r67 = r47 * w45;
    sa[0] = a[0] * (w1 * r01); sa[1] = a[1] * (w0 * r01);
    sa[2] = a[2] * (w3 * r23); sa[3] = a[3] * (w2 * r23);
    sb[0] = b[0] * (w5 * r45); sb[1] = b[1] * (w4 * r45);
    sb[2] = b[2] * (w7 * r67); sb[3] = b[3] * (w6 * r67);
}

// one-time x fp32 -> bf16(x * log2e)  (row-major [N][64])
__global__ __launch_bounds__(1024)
void cvt_x(const float* __restrict__ x, ushort* __restrict__ xb, int n8) {
    int i = blockIdx.x * blockDim.x + threadIdx.x;
    if (i < n8) {
        float4 f0 = *(const float4*)(x + (size_t)i * 8);
        float4 f1 = *(const float4*)(x + (size_t)i * 8 + 4);
        uint4 u;
        u.x = pk2(f0.x * LOG2E_F, f0.y * LOG2E_F);
        u.y = pk2(f0.z * LOG2E_F, f0.w * LOG2E_F);
        u.z = pk2(f1.x * LOG2E_F, f1.y * LOG2E_F);
        u.w = pk2(f1.z * LOG2E_F, f1.w * LOG2E_F);
        *(uint4*)(xb + (size_t)i * 8) = u;
    }
}

// Channel-permuted weight staging: tile T, row R holds physical channel
//   ch(T,R) = 32*(T>>1) + 8*(R>>2) + 4*(T&1) + (R&3)
// -> each layer's MFMA C-output registers ARE the next layer's B-operand
// fragments (register-local handoff, zero main-loop barriers/slab).
// R14 base (164.5us). R15: s_setprio around MFMA clusters (T5; barrier-free
// desynced waves = the regime where it measured +4-7%) + group-8 rcp.
template<int BF16X>
__global__ __launch_bounds__(1024, 1)
void subnet_mlp(const float* __restrict__ x,  const ushort* __restrict__ xbf,
                const float* __restrict__ W1, const float* __restrict__ b1,
                const float* __restrict__ Wh, const float* __restrict__ bh,
                const float* __restrict__ Wo, const float* __restrict__ bo,
                float* __restrict__ out, int n_iters)
{
    __shared__ __align__(16) short sW1[8 * 16 * 64];       // 16 KB
    __shared__ __align__(16) short sWh[2 * 8 * 16 * 128];  // 64 KB
    __shared__ __align__(16) float sBias[512];             // 2 KB (scaled)

    const int tid   = threadIdx.x;
    const int o     = blockIdx.x >> 3;
    const int slice = blockIdx.x & 7;

    char* const cW1 = (char*)sW1;
    char* const cWh = (char*)sWh;
    char* const cB  = (char*)sBias;

    {   // W1 staging: 1024 tasks (T,R,kg)  (weights UNscaled)
        const int R = tid & 15, T = (tid >> 4) & 7, kg = tid >> 7;
        const int c = 32 * (T >> 1) + 8 * (R >> 2) + 4 * (T & 1) + (R & 3);
        const float* p = W1 + ((size_t)o * IN_DIM + kg * 8) * HID + c;
        union { v8s v; unsigned u[4]; } cv;
        #pragma unroll
        for (int j = 0; j < 4; ++j)
            cv.u[j] = pk2(p[(2 * j) * HID], p[(2 * j + 1) * HID]);
        *(v8s*)(cW1 + T * 2048 + R * 128 + ((kg * 16) ^ ((R & 7) << 4))) = cv.v;
    }
    #pragma unroll
    for (int r = 0; r < 4; ++r) {   // Wh staging: 4096 tasks
        const int t = tid + r * 1024;
        const int R = t & 15, T = (t >> 4) & 7, kg = (t >> 7) & 15, l = t >> 11;
        const int c = 32 * (T >> 1) + 8 * (R >> 2) + 4 * (T & 1) + (R & 3);
        const float* p = Wh + (((size_t)l * OUT_DIM + o) * HID + kg * 8) * HID + c;
        union { v8s v; unsigned u[4]; } cv;
        #pragma unroll
        for (int j = 0; j < 4; ++j)
            cv.u[j] = pk2(p[(2 * j) * HID], p[(2 * j + 1) * HID]);
        *(v8s*)(cWh + l * 32768 + T * 4096 + R * 256 + ((kg * 16) ^ ((R & 7) << 4))) = cv.v;
    }
    if (tid < 512) {   // biases *log2e (exp2 domain); head weights *ln2 (undo)
        const int idx = tid & 127, seg = tid >> 7;
        float v;
        if      (seg == 0) v = b1[o * HID + idx] * LOG2E_F;
        else if (seg == 1) v = bh[o * HID + idx] * LOG2E_F;
        else if (seg == 2) v = bh[(OUT_DIM + o) * HID + idx] * LOG2E_F;
        else               v = Wo[o * HID + idx] * LN2_F;
        sBias[tid] = v;
    }
    __syncthreads();   // the ONLY block-wide barrier

    const int lane = tid & 63;
    const int w    = tid >> 6;
    const int n    = lane & 15;
    const int q    = lane >> 4;
    const float bo_v = bo[o];

    int kW1[2], kWh[4];
    #pragma unroll
    for (int kc = 0; kc < 2; ++kc) kW1[kc] = ((4 * kc + q) ^ (n & 7)) << 4;
    #pragma unroll
    for (int kc = 0; kc < 4; ++kc) kWh[kc] = ((4 * kc + q) ^ (n & 7)) << 4;

    const int w1base = n * 128;
    const int whbase = n * 256;
    const int bbase  = 32 * q;

    // ---- x fragment prefetch state (rotated each iteration) ----
    v8s xa0, xa1;
    if constexpr (BF16X) {
        const int row0 = (slice * n_iters + 0) * 256 + w * 16 + n;
        const char* xr = (const char*)(xbf + (size_t)row0 * IN_DIM) + q * 16;
        xa0 = *(const v8s*)(xr);
        xa1 = *(const v8s*)(xr + 64);
    }

    for (int it = 0; it < n_iters; ++it) {
        unsigned z = 0;
        asm volatile("" : "+v"(z));        // anti-LICM launder (R4 lesson)
        const char* const W1p = cW1 + w1base + z;
        const char* const Whp = cWh + whbase + z;
        const char* const Bp  = cB  + bbase  + z;

        const int row = (slice * n_iters + it) * 256 + w * 16 + n;

        v8s xb[2];
        if constexpr (BF16X) {
            xb[0] = xa0;
            xb[1] = xa1;
        } else {
            #pragma unroll
            for (int kc = 0; kc < 2; ++kc) {   // fallback: scale by log2e here
                const float* xp = x + (size_t)row * IN_DIM + kc * 32 + q * 8;
                float4 f0 = *(const float4*)xp;
                float4 f1 = *(const float4*)(xp + 4);
                union { v8s v; unsigned u[4]; } cv;
                cv.u[0] = pk2(f0.x * LOG2E_F, f0.y * LOG2E_F);
                cv.u[1] = pk2(f0.z * LOG2E_F, f0.w * LOG2E_F);
                cv.u[2] = pk2(f1.x * LOG2E_F, f1.y * LOG2E_F);
                cv.u[3] = pk2(f1.z * LOG2E_F, f1.w * LOG2E_F);
                xb[kc] = cv.v;
            }
        }

        // ---------------- layer 1 ----------------
        v4f acc[8];
        #pragma unroll
        for (int T = 0; T < 8; ++T)
            acc[T] = *(const v4f*)(Bp + 128 * (T >> 1) + 16 * (T & 1));
        __builtin_amdgcn_s_setprio(1);
        #pragma unroll
        for (int kc = 0; kc < 2; ++kc)
            #pragma unroll
            for (int T = 0; T < 8; ++T) {
                v8s a = *(const v8s*)(W1p + T * 2048 + kW1[kc]);
                acc[T] = __builtin_amdgcn_mfma_f32_16x16x32_bf16(a, xb[kc], acc[T], 0, 0, 0);
            }
        __builtin_amdgcn_s_setprio(0);

        // prefetch next iteration's x fragments (full-iteration load-to-use gap)
        if constexpr (BF16X) {
            const int itn  = (it + 1 < n_iters) ? it + 1 : it;
            const int rown = (slice * n_iters + itn) * 256 + w * 16 + n;
            const char* xrn = (const char*)(xbf + (size_t)rown * IN_DIM) + q * 16;
            xa0 = *(const v8s*)(xrn);
            xa1 = *(const v8s*)(xrn + 64);
        }

        unsigned h[16];
        #pragma unroll
        for (int T = 0; T < 8; T += 2) {       // group-8 swish: one rcp / 8 vals
            v4f s0, s1;
            swish8x(acc[T], acc[T + 1], s0, s1);
            h[2 * T]     = pk2hw(s0[0], s0[1]);
            h[2 * T + 1] = pk2hw(s0[2], s0[3]);
            h[2 * T + 2] = pk2hw(s1[0], s1[1]);
            h[2 * T + 3] = pk2hw(s1[2], s1[3]);
        }

        // ---------------- hidden layers ----------------
        #pragma unroll
        for (int l = 0; l < 2; ++l) {
            #pragma unroll
            for (int T = 0; T < 8; ++T)
                acc[T] = *(const v4f*)(Bp + 512 + l * 512 + 128 * (T >> 1) + 16 * (T & 1));
            __builtin_amdgcn_s_setprio(1);
            #pragma unroll
            for (int kc = 0; kc < 4; ++kc) {
                v4u tu = { h[kc * 4 + 0], h[kc * 4 + 1], h[kc * 4 + 2], h[kc * 4 + 3] };
                v8s hbv = __builtin_bit_cast(v8s, tu);
                #pragma unroll
                for (int T = 0; T < 8; ++T) {
                    v8s a = *(const v8s*)(Whp + l * 32768 + T * 4096 + kWh[kc]);
                    acc[T] = __builtin_amdgcn_mfma_f32_16x16x32_bf16(a, hbv, acc[T], 0, 0, 0);
                }
            }
            __builtin_amdgcn_s_setprio(0);
            if (l == 0) {
                #pragma unroll
                for (int T = 0; T < 8; T += 2) {
                    v4f s0, s1;
                    swish8x(acc[T], acc[T + 1], s0, s1);
                    h[2 * T]     = pk2hw(s0[0], s0[1]);
                    h[2 * T + 1] = pk2hw(s0[2], s0[3]);
                    h[2 * T + 2] = pk2hw(s1[0], s1[1]);
                    h[2 * T + 3] = pk2hw(s1[2], s1[3]);
                }
            } else {
                // head: s = swish*log2e, wo pre-scaled by ln2 -> exact
                float p = 0.0f;
                #pragma unroll
                for (int T = 0; T < 8; T += 2) {
                    v4f s0, s1;
                    swish8x(acc[T], acc[T + 1], s0, s1);
                    v4f wo0 = *(const v4f*)(Bp + 1536 + 128 * (T >> 1) + 16 * (T & 1));
                    v4f wo1 = *(const v4f*)(Bp + 1536 + 128 * (T >> 1) + 16 * ((T + 1) & 1));
                    p += s0[0] * wo0[0] + s0[1] * wo0[1] + s0[2] * wo0[2] + s0[3] * wo0[3];
                    p += s1[0] * wo1[0] + s1[1] * wo1[1] + s1[2] * wo1[2] + s1[3] * wo1[3];
                }
                p += __shfl_xor(p, 16);
                p += __shfl_xor(p, 32);
                if (lane < 16)
                    out[(size_t)row * OUT_DIM + o] = p + bo_v;
            }
        }
    }
}

extern "C" void kernel_launch(void* const* d_in, const int* in_sizes, int n_in,
                              void* d_out, int out_size, void* d_ws, size_t ws_size,
                              hipStream_t stream) {
    const float* x  = (const float*)d_in[0];
    const float* W1 = (const float*)d_in[1];
    const float* b1 = (const float*)d_in[2];
    const float* Wh = (const float*)d_in[3];
    const float* bh = (const float*)d_in[4];
    const float* Wo = (const float*)d_in[5];
    const float* bo = (const float*)d_in[6];
    float* out = (float*)d_out;

    const int N       = in_sizes[0] / IN_DIM;  // 32768
    const int n_iters = N / (8 * 256);         // 16

    dim3 grid(OUT_DIM * 8);                    // 256 blocks = 1/CU
    dim3 block(1024);

    const size_t need = (size_t)N * IN_DIM * sizeof(ushort);   // 4 MB
    if (d_ws != nullptr && ws_size >= need) {
        ushort* xbf = (ushort*)d_ws;
        const int n8 = N * IN_DIM / 8;
        cvt_x<<<dim3((n8 + 1023) / 1024), dim3(1024), 0, stream>>>(x, xbf, n8);
        subnet_mlp<1><<<grid, block, 0, stream>>>(x, xbf, W1, b1, Wh, bh, Wo, bo, out, n_iters);
    } else {
        subnet_mlp<0><<<grid, block, 0, stream>>>(x, nullptr, W1, b1, Wh, bh, Wo, bo, out, n_iters);
    }
}

// Round 18
// 191.104 us; speedup vs baseline: 1.1503x; 1.1503x over previous
//
#include <hip/hip_runtime.h>
#include <hip/hip_bf16.h>

#define IN_DIM  64
#define HID     128
#define OUT_DIM 32
#define LOG2E_F 1.4426950408889634f
#define LN2_F   0.6931471805599453f

typedef short    v8s __attribute__((ext_vector_type(8)));
typedef float    v4f __attribute__((ext_vector_type(4)));
typedef unsigned v4u __attribute__((ext_vector_type(4)));

__device__ __forceinline__ unsigned pk2(float a, float b) {
    __hip_bfloat162 p = __float22bfloat162_rn(make_float2(a, b));
    return *(unsigned*)&p;
}
// single-instruction HW pack (RNE): lo->bits[15:0], hi->bits[31:16]
__device__ __forceinline__ unsigned pk2hw(float lo, float hi) {
    unsigned r;
    asm("v_cvt_pk_bf16_f32 %0, %1, %2" : "=v"(r) : "v"(lo), "v"(hi));
    return r;
}

#if __has_builtin(__builtin_amdgcn_exp2f)
// Minimal scaled-domain swish: s = v * rcp(1 + 2^-v), v in exp2 domain.
// R17 lesson: raw asm("v_exp_f32") is invisible to the TRANS-use hazard
// recognizer -> stale reads when the consumer lands adjacent (absmax 1.4).
// __builtin_amdgcn_exp2f emits the same v_exp_f32 (neg modifier folded)
// as a COMPILER-KNOWN instruction -> wait states inserted correctly.
// No clamp needed: finite v, v->-inf side gives e=inf -> rcp=0 -> s=0;
// v->+inf side gives e=0 -> s=v.
__device__ __forceinline__ v4f swish4v(v4f v) {
    v4f s;
    #pragma unroll
    for (int i = 0; i < 4; ++i) {
        float e = __builtin_amdgcn_exp2f(-v[i]);
        float r = __builtin_amdgcn_rcpf(1.0f + e);
        s[i] = v[i] * r;
    }
    return s;
}
#else
// Fallback: R14's verbatim grouped-reciprocal swish (empirically passing,
// 164.5us). Clamp 28: product <= (2^28+1)^4 ~ 1.1e34 < FLT_MAX.
__device__ __forceinline__ float exp2raw(float x) {
    float r;
    asm("v_exp_f32 %0, %1" : "=v"(r) : "v"(x));
    return r;
}
__device__ __forceinline__ v4f swish4v(v4f v) {
    float m0 = fminf(-v[0], 28.0f);
    float m1 = fminf(-v[1], 28.0f);
    float m2 = fminf(-v[2], 28.0f);
    float m3 = fminf(-v[3], 28.0f);
    float e0 = exp2raw(m0), e1 = exp2raw(m1), e2 = exp2raw(m2), e3 = exp2raw(m3);
    float w0 = 1.0f + e0, w1 = 1.0f + e1, w2 = 1.0f + e2, w3 = 1.0f + e3;
    float w01 = w0 * w1, w23 = w2 * w3;
    float r   = __builtin_amdgcn_rcpf(w01 * w23);
    float r01 = r * w23, r23 = r * w01;
    v4f s;
    s[0] = v[0] * (w1 * r01);
    s[1] = v[1] * (w0 * r01);
    s[2] = v[2] * (w3 * r23);
    s[3] = v[3] * (w2 * r23);
    return s;
}
#endif

// one-time x fp32 -> bf16(x * log2e)  (row-major [N][64])
__global__ __launch_bounds__(1024)
void cvt_x(const float* __restrict__ x, ushort* __restrict__ xb, int n8) {
    int i = blockIdx.x * blockDim.x + threadIdx.x;
    if (i < n8) {
        float4 f0 = *(const float4*)(x + (size_t)i * 8);
        float4 f1 = *(const float4*)(x + (size_t)i * 8 + 4);
        uint4 u;
        u.x = pk2(f0.x * LOG2E_F, f0.y * LOG2E_F);
        u.y = pk2(f0.z * LOG2E_F, f0.w * LOG2E_F);
        u.z = pk2(f1.x * LOG2E_F, f1.y * LOG2E_F);
        u.w = pk2(f1.z * LOG2E_F, f1.w * LOG2E_F);
        *(uint4*)(xb + (size_t)i * 8) = u;
    }
}

// Channel-permuted weight staging: tile T, row R holds physical channel
//   ch(T,R) = 32*(T>>1) + 8*(R>>2) + 4*(T&1) + (R&3)
// -> each layer's MFMA C-output registers ARE the next layer's B-operand
// fragments (register-local handoff, zero main-loop barriers/slab).
// R14 base (164.5us): exp2-scaled domain (x,b *log2e; wo *ln2), bf16-x
// workspace, HW pack, x-prefetch, opaque-z anti-LICM launder.
template<int BF16X>
__global__ __launch_bounds__(1024, 1)
void subnet_mlp(const float* __restrict__ x,  const ushort* __restrict__ xbf,
                const float* __restrict__ W1, const float* __restrict__ b1,
                const float* __restrict__ Wh, const float* __restrict__ bh,
                const float* __restrict__ Wo, const float* __restrict__ bo,
                float* __restrict__ out, int n_iters)
{
    __shared__ __align__(16) short sW1[8 * 16 * 64];       // 16 KB
    __shared__ __align__(16) short sWh[2 * 8 * 16 * 128];  // 64 KB
    __shared__ __align__(16) float sBias[512];             // 2 KB (scaled)

    const int tid   = threadIdx.x;
    const int o     = blockIdx.x >> 3;
    const int slice = blockIdx.x & 7;

    char* const cW1 = (char*)sW1;
    char* const cWh = (char*)sWh;
    char* const cB  = (char*)sBias;

    {   // W1 staging: 1024 tasks (T,R,kg)  (weights UNscaled)
        const int R = tid & 15, T = (tid >> 4) & 7, kg = tid >> 7;
        const int c = 32 * (T >> 1) + 8 * (R >> 2) + 4 * (T & 1) + (R & 3);
        const float* p = W1 + ((size_t)o * IN_DIM + kg * 8) * HID + c;
        union { v8s v; unsigned u[4]; } cv;
        #pragma unroll
        for (int j = 0; j < 4; ++j)
            cv.u[j] = pk2(p[(2 * j) * HID], p[(2 * j + 1) * HID]);
        *(v8s*)(cW1 + T * 2048 + R * 128 + ((kg * 16) ^ ((R & 7) << 4))) = cv.v;
    }
    #pragma unroll
    for (int r = 0; r < 4; ++r) {   // Wh staging: 4096 tasks
        const int t = tid + r * 1024;
        const int R = t & 15, T = (t >> 4) & 7, kg = (t >> 7) & 15, l = t >> 11;
        const int c = 32 * (T >> 1) + 8 * (R >> 2) + 4 * (T & 1) + (R & 3);
        const float* p = Wh + (((size_t)l * OUT_DIM + o) * HID + kg * 8) * HID + c;
        union { v8s v; unsigned u[4]; } cv;
        #pragma unroll
        for (int j = 0; j < 4; ++j)
            cv.u[j] = pk2(p[(2 * j) * HID], p[(2 * j + 1) * HID]);
        *(v8s*)(cWh + l * 32768 + T * 4096 + R * 256 + ((kg * 16) ^ ((R & 7) << 4))) = cv.v;
    }
    if (tid < 512) {   // biases *log2e (exp2 domain); head weights *ln2 (undo)
        const int idx = tid & 127, seg = tid >> 7;
        float v;
        if      (seg == 0) v = b1[o * HID + idx] * LOG2E_F;
        else if (seg == 1) v = bh[o * HID + idx] * LOG2E_F;
        else if (seg == 2) v = bh[(OUT_DIM + o) * HID + idx] * LOG2E_F;
        else               v = Wo[o * HID + idx] * LN2_F;
        sBias[tid] = v;
    }
    __syncthreads();   // the ONLY block-wide barrier

    const int lane = tid & 63;
    const int w    = tid >> 6;
    const int n    = lane & 15;
    const int q    = lane >> 4;
    const float bo_v = bo[o];

    int kW1[2], kWh[4];
    #pragma unroll
    for (int kc = 0; kc < 2; ++kc) kW1[kc] = ((4 * kc + q) ^ (n & 7)) << 4;
    #pragma unroll
    for (int kc = 0; kc < 4; ++kc) kWh[kc] = ((4 * kc + q) ^ (n & 7)) << 4;

    const int w1base = n * 128;
    const int whbase = n * 256;
    const int bbase  = 32 * q;

    // ---- x fragment prefetch state (rotated each iteration) ----
    v8s xa0, xa1;
    if constexpr (BF16X) {
        const int row0 = (slice * n_iters + 0) * 256 + w * 16 + n;
        const char* xr = (const char*)(xbf + (size_t)row0 * IN_DIM) + q * 16;
        xa0 = *(const v8s*)(xr);
        xa1 = *(const v8s*)(xr + 64);
    }

    for (int it = 0; it < n_iters; ++it) {
        unsigned z = 0;
        asm volatile("" : "+v"(z));        // anti-LICM launder (R4 lesson)
        const char* const W1p = cW1 + w1base + z;
        const char* const Whp = cWh + whbase + z;
        const char* const Bp  = cB  + bbase  + z;

        const int row = (slice * n_iters + it) * 256 + w * 16 + n;

        v8s xb[2];
        if constexpr (BF16X) {
            xb[0] = xa0;
            xb[1] = xa1;
        } else {
            #pragma unroll
            for (int kc = 0; kc < 2; ++kc) {   // fallback: scale by log2e here
                const float* xp = x + (size_t)row * IN_DIM + kc * 32 + q * 8;
                float4 f0 = *(const float4*)xp;
                float4 f1 = *(const float4*)(xp + 4);
                union { v8s v; unsigned u[4]; } cv;
                cv.u[0] = pk2(f0.x * LOG2E_F, f0.y * LOG2E_F);
                cv.u[1] = pk2(f0.z * LOG2E_F, f0.w * LOG2E_F);
                cv.u[2] = pk2(f1.x * LOG2E_F, f1.y * LOG2E_F);
                cv.u[3] = pk2(f1.z * LOG2E_F, f1.w * LOG2E_F);
                xb[kc] = cv.v;
            }
        }

        // ---------------- layer 1 ----------------
        v4f acc[8];
        #pragma unroll
        for (int T = 0; T < 8; ++T)
            acc[T] = *(const v4f*)(Bp + 128 * (T >> 1) + 16 * (T & 1));
        #pragma unroll
        for (int kc = 0; kc < 2; ++kc)
            #pragma unroll
            for (int T = 0; T < 8; ++T) {
                v8s a = *(const v8s*)(W1p + T * 2048 + kW1[kc]);
                acc[T] = __builtin_amdgcn_mfma_f32_16x16x32_bf16(a, xb[kc], acc[T], 0, 0, 0);
            }

        // prefetch next iteration's x fragments (full-iteration load-to-use gap)
        if constexpr (BF16X) {
            const int itn  = (it + 1 < n_iters) ? it + 1 : it;
            const int rown = (slice * n_iters + itn) * 256 + w * 16 + n;
            const char* xrn = (const char*)(xbf + (size_t)rown * IN_DIM) + q * 16;
            xa0 = *(const v8s*)(xrn);
            xa1 = *(const v8s*)(xrn + 64);
        }

        unsigned h[16];
        #pragma unroll
        for (int T = 0; T < 8; ++T) {
            v4f s = swish4v(acc[T]);       // s = swish*log2e = next-layer input
            const int i0 = (T >> 1) * 4 + 2 * (T & 1);
            h[i0]     = pk2hw(s[0], s[1]);
            h[i0 + 1] = pk2hw(s[2], s[3]);
        }

        // ---------------- hidden layers ----------------
        #pragma unroll
        for (int l = 0; l < 2; ++l) {
            #pragma unroll
            for (int T = 0; T < 8; ++T)
                acc[T] = *(const v4f*)(Bp + 512 + l * 512 + 128 * (T >> 1) + 16 * (T & 1));
            #pragma unroll
            for (int kc = 0; kc < 4; ++kc) {
                v4u tu = { h[kc * 4 + 0], h[kc * 4 + 1], h[kc * 4 + 2], h[kc * 4 + 3] };
                v8s hbv = __builtin_bit_cast(v8s, tu);
                #pragma unroll
                for (int T = 0; T < 8; ++T) {
                    v8s a = *(const v8s*)(Whp + l * 32768 + T * 4096 + kWh[kc]);
                    acc[T] = __builtin_amdgcn_mfma_f32_16x16x32_bf16(a, hbv, acc[T], 0, 0, 0);
                }
            }
            if (l == 0) {
                #pragma unroll
                for (int T = 0; T < 8; ++T) {
                    v4f s = swish4v(acc[T]);
                    const int i0 = (T >> 1) * 4 + 2 * (T & 1);
                    h[i0]     = pk2hw(s[0], s[1]);
                    h[i0 + 1] = pk2hw(s[2], s[3]);
                }
            } else {
                // head: s = swish*log2e, wo pre-scaled by ln2 -> exact
                float p = 0.0f;
                #pragma unroll
                for (int T = 0; T < 8; ++T) {
                    v4f wo = *(const v4f*)(Bp + 1536 + 128 * (T >> 1) + 16 * (T & 1));
                    v4f s  = swish4v(acc[T]);
                    p += s[0] * wo[0];
                    p += s[1] * wo[1];
                    p += s[2] * wo[2];
                    p += s[3] * wo[3];
                }
                p += __shfl_xor(p, 16);
                p += __shfl_xor(p, 32);
                if (lane < 16)
                    out[(size_t)row * OUT_DIM + o] = p + bo_v;
            }
        }
    }
}

extern "C" void kernel_launch(void* const* d_in, const int* in_sizes, int n_in,
                              void* d_out, int out_size, void* d_ws, size_t ws_size,
                              hipStream_t stream) {
    const float* x  = (const float*)d_in[0];
    const float* W1 = (const float*)d_in[1];
    const float* b1 = (const float*)d_in[2];
    const float* Wh = (const float*)d_in[3];
    const float* bh = (const float*)d_in[4];
    const float* Wo = (const float*)d_in[5];
    const float* bo = (const float*)d_in[6];
    float* out = (float*)d_out;

    const int N       = in_sizes[0] / IN_DIM;  // 32768
    const int n_iters = N / (8 * 256);         // 16

    dim3 grid(OUT_DIM * 8);                    // 256 blocks = 1/CU
    dim3 block(1024);

    const size_t need = (size_t)N * IN_DIM * sizeof(ushort);   // 4 MB
    if (d_ws != nullptr && ws_size >= need) {
        ushort* xbf = (ushort*)d_ws;
        const int n8 = N * IN_DIM / 8;
        cvt_x<<<dim3((n8 + 1023) / 1024), dim3(1024), 0, stream>>>(x, xbf, n8);
        subnet_mlp<1><<<grid, block, 0, stream>>>(x, xbf, W1, b1, Wh, bh, Wo, bo, out, n_iters);
    } else {
        subnet_mlp<0><<<grid, block, 0, stream>>>(x, nullptr, W1, b1, Wh, bh, Wo, bo, out, n_iters);
    }
}